// Round 2
// baseline (633.680 us; speedup 1.0000x reference)
//
#include <hip/hip_runtime.h>
#include <hip/hip_bf16.h>
#include <stdint.h>

// VenomSpmm: y = x @ (W*mask)^T + bias, mask keeps k%8 in {0,2} (2:8 structured).
// Inputs/outputs are FP32 (per reference dtypes). Effective dense GEMM:
// M=16384, N=4096, Kc=1024.
//
// Phase 1: compact+convert fp32 -> bf16 into d_ws (keep elems 0,2 of every 8;
//          both live in the first 16B of each 32B group -> one float4 load).
// Phase 2: m97-style 128x128x32 bf16 MFMA GEMM, fp32 accumulate, fp32 out.

typedef __attribute__((ext_vector_type(8))) short short8;   // 8 bf16 = 4 VGPRs
typedef __attribute__((ext_vector_type(4))) float float4_t; // 4 fp32 acc

typedef unsigned short u16;
typedef unsigned int   u32;

#define M_TOT 16384
#define N_TOT 4096
#define K_ACT 4096
#define K_C   1024

typedef __attribute__((address_space(1))) void GlobVoid;
typedef __attribute__((address_space(3))) void LdsVoid;

static __device__ __forceinline__ u32 f32_to_bf16_rne(float f) {
    u32 u = __float_as_uint(f);
    u32 rounded = u + 0x7FFFu + ((u >> 16) & 1u);
    return rounded >> 16;
}

// ---- compaction: one 8-fp32 group (32B) -> 2 bf16 (4B); need only first 16B ----
__global__ __launch_bounds__(256) void compact_k(const float4* __restrict__ src,
                                                 u32* __restrict__ dst, int n) {
    int i = blockIdx.x * 256 + threadIdx.x;
    if (i >= n) return;
    float4 g = src[(size_t)i * 2];  // first 16B of the 32B group: e0,e1,e2,e3
    dst[i] = f32_to_bf16_rne(g.x) | (f32_to_bf16_rne(g.z) << 16);
}

// ---- main GEMM: C[m,n] = sum_k A[m,k]*B[n,k] + bias[n] ----
// A = x_c [M, Kc] row-major bf16, B = W_c [N, Kc] row-major bf16.
__global__ __launch_bounds__(256) void gemm_bt(const u16* __restrict__ A,
                                               const u16* __restrict__ B,
                                               const float* __restrict__ bias,
                                               float* __restrict__ C) {
    __shared__ u16 Als[128 * 32];  // 8 KB, row-major, 32 bf16 per row (64B)
    __shared__ u16 Bls[128 * 32];  // 8 KB

    const int tid  = threadIdx.x;
    const int lane = tid & 63;
    const int wave = tid >> 6;
    const int m0   = blockIdx.y * 128;
    const int n0   = blockIdx.x * 128;

    const int wm = (wave & 1) * 64;   // wave's 64x64 quadrant
    const int wn = (wave >> 1) * 64;
    const int fr = lane & 15;         // fragment m/n index (within 16)
    const int kq = (lane >> 4) * 8;   // k offset of this quad (8 bf16 = 16B)

    // staging: each global_load_lds stages 1KB per wave (64 lanes x 16B),
    // HW dest = wave-uniform base + lane*16B. Source must match that order:
    const int srow = lane >> 2;       // row within 16-row chunk
    const int scol = (lane & 3) * 8;  // u16 offset within 64B row

    float4_t acc[4][4];
    const float4_t fzero = {0.f, 0.f, 0.f, 0.f};
#pragma unroll
    for (int i = 0; i < 4; ++i)
#pragma unroll
        for (int j = 0; j < 4; ++j) acc[i][j] = fzero;

    for (int kt = 0; kt < K_C; kt += 32) {
        __syncthreads();  // protect LDS from previous iteration's readers
#pragma unroll
        for (int c = 0; c < 2; ++c) {
            const int ch  = wave * 2 + c;
            const int row = ch * 16 + srow;
            const u16* ga = A + (size_t)(m0 + row) * K_C + kt + scol;
            __builtin_amdgcn_global_load_lds((GlobVoid*)ga, (LdsVoid*)&Als[ch * 512],
                                             16, 0, 0);
            const u16* gb = B + (size_t)(n0 + row) * K_C + kt + scol;
            __builtin_amdgcn_global_load_lds((GlobVoid*)gb, (LdsVoid*)&Bls[ch * 512],
                                             16, 0, 0);
        }
        __syncthreads();  // compiler drains vmcnt before barrier

        short8 af[4], bf[4];
#pragma unroll
        for (int i = 0; i < 4; ++i)
            af[i] = *(const short8*)&Als[(wm + i * 16 + fr) * 32 + kq];
#pragma unroll
        for (int j = 0; j < 4; ++j)
            bf[j] = *(const short8*)&Bls[(wn + j * 16 + fr) * 32 + kq];

#pragma unroll
        for (int i = 0; i < 4; ++i)
#pragma unroll
            for (int j = 0; j < 4; ++j)
                acc[i][j] = __builtin_amdgcn_mfma_f32_16x16x32_bf16(
                    af[i], bf[j], acc[i][j], 0, 0, 0);
    }

    // epilogue: D mapping col = lane&15, row = (lane>>4)*4 + reg (verified m89/m91)
    const int rbase = m0 + wm + (lane >> 4) * 4;
    const int cbase = n0 + wn + fr;
#pragma unroll
    for (int j = 0; j < 4; ++j) {
        const int col  = cbase + j * 16;
        const float bj = bias[col];
#pragma unroll
        for (int i = 0; i < 4; ++i) {
            const int row = rbase + i * 16;
#pragma unroll
            for (int r = 0; r < 4; ++r) {
                C[(size_t)(row + r) * N_TOT + col] = acc[i][j][r] + bj;
            }
        }
    }
}

// ---- fallback (only if ws too small): slow but correct, pure fp32 ----
__global__ __launch_bounds__(256) void fallback_k(const float* __restrict__ X,
                                                  const float* __restrict__ W,
                                                  const float* __restrict__ bias,
                                                  float* __restrict__ out) {
    size_t idx = (size_t)blockIdx.x * 256 + threadIdx.x;
    int n    = (int)(idx & (N_TOT - 1));
    size_t m = idx >> 12;
    const float* xr = X + m * K_ACT;
    const float* wr = W + (size_t)n * K_ACT;
    float acc = 0.f;
    for (int g = 0; g < K_ACT / 8; ++g) {
        acc += xr[g * 8] * wr[g * 8] + xr[g * 8 + 2] * wr[g * 8 + 2];
    }
    out[idx] = acc + bias[n];
}

extern "C" void kernel_launch(void* const* d_in, const int* in_sizes, int n_in,
                              void* d_out, int out_size, void* d_ws, size_t ws_size,
                              hipStream_t stream) {
    const float* x    = (const float*)d_in[0];   // [16384, 4096] fp32
    const float* w    = (const float*)d_in[1];   // [4096, 4096] fp32
    const float* bias = (const float*)d_in[2];   // [4096] fp32
    float* out = (float*)d_out;                  // [16384, 4096] fp32

    const size_t xc_elems = (size_t)M_TOT * K_C;             // 16M u16 = 33.5 MB
    const size_t wc_elems = (size_t)N_TOT * K_C;             //  4M u16 =  8.4 MB
    const size_t need = (xc_elems + wc_elems) * sizeof(u16);

    if (ws_size >= need) {
        u16* xc = (u16*)d_ws;
        u16* wc = xc + xc_elems;

        const int ngx = M_TOT * (K_ACT / 8);                 // 8,388,608 groups
        const int ngw = N_TOT * (K_ACT / 8);                 // 2,097,152 groups
        compact_k<<<ngx / 256, 256, 0, stream>>>((const float4*)x, (u32*)xc, ngx);
        compact_k<<<ngw / 256, 256, 0, stream>>>((const float4*)w, (u32*)wc, ngw);

        dim3 grid(N_TOT / 128, M_TOT / 128);                 // 32 x 128 = 4096 blocks
        gemm_bt<<<grid, 256, 0, stream>>>(xc, wc, bias, out);
    } else {
        const size_t total = (size_t)M_TOT * N_TOT;
        fallback_k<<<(int)(total / 256), 256, 0, stream>>>(x, w, bias, out);
    }
}